// Round 7
// baseline (211.117 us; speedup 1.0000x reference)
//
#include <hip/hip_runtime.h>

typedef unsigned char u8;
typedef float fp32x4 __attribute__((ext_vector_type(4)));
typedef long lx2 __attribute__((ext_vector_type(2)));

#define BS 4096
#define NROW 8192
#define D 512
#define TILE 128
#define NB (NROW / TILE)          // 64 block-rows/cols
#define NBLK (NB * (NB + 1) / 2)  // 2080 upper-triangle tiles
#define NPBLK 256                 // persistent blocks; 1/CU (LDS-bound), all co-resident
#define NTHR 256                  // 4 waves
#define INV_T 10.0f

// Packed An layout (verified R2: bank conflicts 1.28e7 -> 2.1e6).
// 8-byte chunk L = k>>3 of row r:
//   off(r, L) = (r>>4)*8192 + (L>>3)*1024 + (r&15)*64
//             + (((L&3) ^ ((r&15)>>2)) << 4) + (((L>>2)&1) << 3)
// Consumer lane (fr=l&15, h=l>>4): one ds_read_b128 per (rowgrp, p) covering
// ks=2p,2p+1 at rowgrp*8192 + p*1024 + fr*64 + ((h^(fr>>2))&3)*16 ->
// bank-bijective per 16-lane quarter (2 words/bank = structural floor).

__device__ __forceinline__ void g2l16(const void* g, void* l) {
  __builtin_amdgcn_global_load_lds(
      (const __attribute__((address_space(1))) unsigned int*)g,
      (__attribute__((address_space(3))) unsigned int*)l, 16, 0, 0);
}

// stage one 128-row strip (64 KB contiguous) into LDS; 16 g2l16 per thread
__device__ __forceinline__ void stage_strip(const u8* __restrict__ g,
                                            u8* __restrict__ l, int tid) {
#pragma unroll
  for (int it = 0; it < 16; ++it)
    g2l16(g + it * 4096 + tid * 16, l + it * 4096 + tid * 16);
}

// ONE persistent kernel: normalize (32 rows/block) -> device barrier ->
// R2-structure triangle GEMM (full-K LDS, best measured: 69.4us) ->
// last-block finalize. Removes two kernel-launch boundaries (~10-17us each
// measured across R0..R6).
__global__ __launch_bounds__(NTHR) void infonce_k(
    const float* __restrict__ zi, const float* __restrict__ zj,
    u8* __restrict__ An, float* __restrict__ den, float* __restrict__ posAcc,
    int* __restrict__ doneNorm, int* __restrict__ done2,
    float* __restrict__ out) {
  __shared__ __align__(16) u8 sA[TILE * D];  // 64 KB
  __shared__ __align__(16) u8 sB[TILE * D];  // 64 KB
  __shared__ float redbuf[4];
  __shared__ int lastFlag;

  const int tid = threadIdx.x;
  const int lane = tid & 63;
  const int wave = tid >> 6;

  // ---- phase 1: normalize this block's 32 rows -> packed fp8 ----
  {
    const int rbase = blockIdx.x * 32 + wave * 8;
#pragma unroll
    for (int q = 0; q < 8; ++q) {
      const int r = rbase + q;
      const float* src =
          (r < BS) ? (zi + (size_t)r * D) : (zj + (size_t)(r - BS) * D);
      const float4 v0 = ((const float4*)src)[lane * 2];
      const float4 v1 = ((const float4*)src)[lane * 2 + 1];
      float ss = v0.x * v0.x + v0.y * v0.y + v0.z * v0.z + v0.w * v0.w +
                 v1.x * v1.x + v1.y * v1.y + v1.z * v1.z + v1.w * v1.w;
#pragma unroll
      for (int off = 1; off < 64; off <<= 1) ss += __shfl_xor(ss, off);
      const float inv = 1.0f / fmaxf(sqrtf(ss), 1e-8f);
      int lo = __builtin_amdgcn_cvt_pk_fp8_f32(v0.x * inv, v0.y * inv, 0, false);
      lo = __builtin_amdgcn_cvt_pk_fp8_f32(v0.z * inv, v0.w * inv, lo, true);
      int hi = __builtin_amdgcn_cvt_pk_fp8_f32(v1.x * inv, v1.y * inv, 0, false);
      hi = __builtin_amdgcn_cvt_pk_fp8_f32(v1.z * inv, v1.w * inv, hi, true);
      const int r16 = r & 15;
      const int off = ((r >> 4) << 13) + ((lane >> 3) << 10) + (r16 << 6) +
                      ((((lane & 3) ^ (r16 >> 2)) & 3) << 4) +
                      (((lane >> 2) & 1) << 3);
      *(int2*)(An + off) = make_int2(lo, hi);
    }
  }

  // ---- device barrier (all 256 blocks co-resident: 1/CU x 256 CU) ----
  __threadfence();  // release our An writes device-wide
  __syncthreads();  // all waves' stores issued before tid0 signals
  if (tid == 0) {
    __hip_atomic_fetch_add(doneNorm, 1, __ATOMIC_RELEASE,
                           __HIP_MEMORY_SCOPE_AGENT);
    while (__hip_atomic_load(doneNorm, __ATOMIC_ACQUIRE,
                             __HIP_MEMORY_SCOPE_AGENT) != NPBLK)
      __builtin_amdgcn_s_sleep(2);
  }
  __syncthreads();
  __threadfence();  // acquire: invalidate stale An lines before reads

  // ---- phase 2: triangle GEMM, R2 structure (verbatim) ----
  const int wr = wave >> 1;  // 64-row band within the 128x128 tile
  const int wc = wave & 1;   // 64-col band
  const int fr = lane & 15;
  const int h = lane >> 4;

  // contiguous chunk [t0, t1) of triangle tiles (8 or 9 per block)
  const int t0 = (int)(((long)blockIdx.x * NBLK) >> 8);
  const int t1 = (int)(((long)(blockIdx.x + 1) * NBLK) >> 8);

  int rem = t0, bi = 0;
  while (rem >= NB - bi) { rem -= NB - bi; ++bi; }
  int bj = bi + rem;

  stage_strip(An + (size_t)bi * 65536, sA, tid);
  stage_strip(An + (size_t)bj * 65536, sB, tid);
  __syncthreads();  // drains vmcnt -> tiles resident

  // per-lane fragment base: one b128 per (rowgrp, p) covers ks=2p, 2p+1
  const int fbase = fr * 64 + ((h ^ (fr >> 2)) & 3) * 16;
  const u8* pa = sA + wr * 32768 + fbase;
  const u8* pb = sB + wc * 32768 + fbase;

  for (int t = t0; t < t1; ++t) {
    fp32x4 acc[4][4] = {};
    // full-K compute: no barriers; 64 ds_read_b128 + 512 MFMA per wave
#pragma unroll
    for (int p = 0; p < 8; ++p) {
      lx2 a[4], b[4];
#pragma unroll
      for (int i = 0; i < 4; ++i) {
        a[i] = *(const lx2*)(pa + i * 8192 + p * 1024);
        b[i] = *(const lx2*)(pb + i * 8192 + p * 1024);
      }
#pragma unroll
      for (int i = 0; i < 4; ++i)
#pragma unroll
        for (int j = 0; j < 4; ++j)
          acc[i][j] = __builtin_amdgcn_mfma_f32_16x16x32_fp8_fp8(
              a[i][0], b[j][0], acc[i][j], 0, 0, 0);
#pragma unroll
      for (int i = 0; i < 4; ++i)
#pragma unroll
        for (int j = 0; j < 4; ++j)
          acc[i][j] = __builtin_amdgcn_mfma_f32_16x16x32_fp8_fp8(
              a[i][1], b[j][1], acc[i][j], 0, 0, 0);
    }
    __syncthreads();  // every wave done reading sA/sB

    // issue next tile's staging NOW; the DMA runs under the epilogue below
    int nbi = bi, nbj = bj + 1;
    if (nbj == NB) { ++nbi; nbj = nbi; }
    if (t + 1 < t1) {
      if (nbi != bi) stage_strip(An + (size_t)nbi * 65536, sA, tid);
      stage_strip(An + (size_t)nbj * 65536, sB, tid);
    }

    // Epilogue (register-only + atomics; safe while DMA overwrites LDS).
    // C/D layout: col = lane&15, row = (lane>>4)*4 + reg.
    const bool diag = (bi == bj);
    const int rowBase = bi * TILE;
    const int colBase = bj * TILE;
    const int rq = h * 4;
    float posPart = 0.0f;
    float colAcc[4] = {0.0f, 0.0f, 0.0f, 0.0f};
#pragma unroll
    for (int i = 0; i < 4; ++i) {
      const int rbase = rowBase + wr * 64 + i * 16 + rq;
      float rs[4] = {0.0f, 0.0f, 0.0f, 0.0f};
#pragma unroll
      for (int j = 0; j < 4; ++j) {
        const int colg = colBase + wc * 64 + j * 16 + fr;
        fp32x4 v = acc[i][j];
#pragma unroll
        for (int rg = 0; rg < 4; ++rg) {
          const int rowg = rbase + rg;
          const float sv = v[rg] * INV_T;
          float e = __expf(sv);
          if (diag && rowg == colg) e = 0.0f;  // exclude exact diagonal
          rs[rg] += e;
          colAcc[j] += e;
          if (colg == rowg + BS) posPart += sv;  // upper copy; doubled later
        }
      }
#pragma unroll
      for (int rg = 0; rg < 4; ++rg) {
        float s = rs[rg];
        s += __shfl_xor(s, 1);
        s += __shfl_xor(s, 2);
        s += __shfl_xor(s, 4);
        s += __shfl_xor(s, 8);
        if (fr == 0) atomicAdd(&den[rbase + rg], s);
      }
    }
    if (!diag) {
#pragma unroll
      for (int j = 0; j < 4; ++j) {
        float c = colAcc[j];
        c += __shfl_xor(c, 16);
        c += __shfl_xor(c, 32);
        if (h == 0) atomicAdd(&den[colBase + wc * 64 + j * 16 + fr], c);
      }
    }
    posPart += __shfl_xor(posPart, 1);
    posPart += __shfl_xor(posPart, 2);
    posPart += __shfl_xor(posPart, 4);
    posPart += __shfl_xor(posPart, 8);
    posPart += __shfl_xor(posPart, 16);
    posPart += __shfl_xor(posPart, 32);
    if (lane == 0 && posPart != 0.0f) atomicAdd(posAcc, posPart);

    __syncthreads();  // drains vmcnt -> next tile staged; LDS reuse safe
    bi = nbi;
    bj = nbj;
  }

  // ---- phase 3: fused finalize by the last block to finish ----
  __threadfence();  // device-scope: den/posAcc atomics visible
  if (tid == 0) lastFlag = (atomicAdd(done2, 1) == NPBLK - 1);
  __syncthreads();
  if (lastFlag) {
    float s = 0.0f;
    for (int i = tid; i < NROW; i += NTHR)
      s += logf(__hip_atomic_load(&den[i], __ATOMIC_RELAXED,
                                  __HIP_MEMORY_SCOPE_AGENT));
#pragma unroll
    for (int off = 1; off < 64; off <<= 1) s += __shfl_xor(s, off);
    if (lane == 0) redbuf[wave] = s;
    __syncthreads();
    if (tid == 0) {
      float tot = redbuf[0] + redbuf[1] + redbuf[2] + redbuf[3];
      const float pos = __hip_atomic_load(posAcc, __ATOMIC_RELAXED,
                                          __HIP_MEMORY_SCOPE_AGENT);
      // each unordered positive pair was counted once -> double it
      out[0] = (tot - 2.0f * pos) * (1.0f / (float)NROW);
    }
  }
}

extern "C" void kernel_launch(void* const* d_in, const int* in_sizes, int n_in,
                              void* d_out, int out_size, void* d_ws, size_t ws_size,
                              hipStream_t stream) {
  const float* zi = (const float*)d_in[0];
  const float* zj = (const float*)d_in[1];
  float* out = (float*)d_out;

  u8* An = (u8*)d_ws;                                      // 4 MB packed fp8
  float* den = (float*)((char*)d_ws + (size_t)NROW * D);   // 8192 fp32
  float* posAcc = den + NROW;                              // 1 fp32
  int* doneNorm = (int*)(posAcc + 1);                      // barrier counter
  int* done2 = doneNorm + 1;                               // finalize counter

  // zero den + posAcc + doneNorm + done2 (graph-capturable async memset)
  hipMemsetAsync(den, 0, (size_t)NROW * 4 + 12, stream);
  infonce_k<<<NPBLK, NTHR, 0, stream>>>(zi, zj, An, den, posAcc, doneNorm,
                                        done2, out);
}

// Round 8
// 149.309 us; speedup vs baseline: 1.4140x; 1.4140x over previous
//
#include <hip/hip_runtime.h>

typedef unsigned char u8;
typedef float fp32x4 __attribute__((ext_vector_type(4)));
typedef long lx2 __attribute__((ext_vector_type(2)));

#define BS 4096
#define NROW 8192
#define D 512
#define TILE 128
#define NB (NROW / TILE)          // 64 block-rows/cols
#define NBLK (NB * (NB + 1) / 2)  // 2080 upper-triangle tiles
#define NPBLK 256                 // persistent workgroups (1 per CU)
#define NTHR 256                  // 4 waves
// An = z_hat * sqrt(10*log2(e))  ->  acc = sim*10*log2(e)  ->
// exp(sim*10) = v_exp_f32(acc) directly (v_exp_f32 computes 2^x).
#define SCALE 3.79828286f
#define LN2 0.69314718f

// Packed An layout (verified R2: bank conflicts 1.28e7 -> 2.1e6).
// 8-byte chunk L = k>>3 of row r:
//   off(r, L) = (r>>4)*8192 + (L>>3)*1024 + (r&15)*64
//             + (((L&3) ^ ((r&15)>>2)) << 4) + (((L>>2)&1) << 3)
// Consumer lane (fr=l&15, h=l>>4): one ds_read_b128 per (rowgrp, p) covering
// ks=2p,2p+1 at rowgrp*8192 + p*1024 + fr*64 + ((h^(fr>>2))&3)*16 ->
// bank-bijective per 16-lane quarter (2 words/bank = structural floor).

__device__ __forceinline__ void g2l16(const void* g, void* l) {
  __builtin_amdgcn_global_load_lds(
      (const __attribute__((address_space(1))) unsigned int*)g,
      (__attribute__((address_space(3))) unsigned int*)l, 16, 0, 0);
}

// stage one 128-row strip (64 KB contiguous) into LDS; 16 g2l16 per thread
__device__ __forceinline__ void stage_strip(const u8* __restrict__ g,
                                            u8* __restrict__ l, int tid) {
#pragma unroll
  for (int it = 0; it < 16; ++it)
    g2l16(g + it * 4096 + tid * 16, l + it * 4096 + tid * 16);
}

// Wave-per-row normalize -> fp8 e4m3 (scaled), packed+swizzled layout.
// Also zeroes den/posAcc/done (ws is re-poisoned before every launch).
__global__ __launch_bounds__(256) void normalize_k(
    const float* __restrict__ zi, const float* __restrict__ zj,
    u8* __restrict__ An, float* __restrict__ den, float* __restrict__ posAcc,
    int* __restrict__ done) {
  const int lane = threadIdx.x & 63;
  const int wave = threadIdx.x >> 6;
  const int r = blockIdx.x * 4 + wave;
  const float* src = (r < BS) ? (zi + (size_t)r * D) : (zj + (size_t)(r - BS) * D);
  const float4 v0 = ((const float4*)src)[lane * 2];
  const float4 v1 = ((const float4*)src)[lane * 2 + 1];
  float ss = v0.x * v0.x + v0.y * v0.y + v0.z * v0.z + v0.w * v0.w +
             v1.x * v1.x + v1.y * v1.y + v1.z * v1.z + v1.w * v1.w;
#pragma unroll
  for (int off = 1; off < 64; off <<= 1) ss += __shfl_xor(ss, off);
  const float inv = SCALE / fmaxf(sqrtf(ss), 1e-8f);
  int lo = __builtin_amdgcn_cvt_pk_fp8_f32(v0.x * inv, v0.y * inv, 0, false);
  lo = __builtin_amdgcn_cvt_pk_fp8_f32(v0.z * inv, v0.w * inv, lo, true);
  int hi = __builtin_amdgcn_cvt_pk_fp8_f32(v1.x * inv, v1.y * inv, 0, false);
  hi = __builtin_amdgcn_cvt_pk_fp8_f32(v1.z * inv, v1.w * inv, hi, true);
  // lane holds chunk L = lane (k = 8*lane .. +8)
  const int r16 = r & 15;
  const int off = ((r >> 4) << 13) + ((lane >> 3) << 10) + (r16 << 6) +
                  ((((lane & 3) ^ (r16 >> 2)) & 3) << 4) + (((lane >> 2) & 1) << 3);
  *(int2*)(An + off) = make_int2(lo, hi);
  if (lane == 0) den[r] = 0.0f;
  if (r == 0 && lane == 0) { posAcc[0] = 0.0f; *done = 0; }
}

// Persistent full-K triangle GEMM (R2 structure, best measured: 69.4us).
// Each block owns ~8 contiguous triangle tiles; LDS holds full-K A and B
// strips -> zero barriers in the K loop. Per tile: compute -> barrier ->
// issue next-tile DMA -> epilogue (overlaps DMA) -> barrier.
// Last block to finish computes the loss (device-scope atomics).
__global__ __launch_bounds__(NTHR) void gemm_expsum(
    const u8* __restrict__ An, float* __restrict__ den,
    float* __restrict__ posAcc, int* __restrict__ done,
    float* __restrict__ out) {
  __shared__ __align__(16) u8 sA[TILE * D];  // 64 KB
  __shared__ __align__(16) u8 sB[TILE * D];  // 64 KB
  __shared__ float redbuf[4];
  __shared__ int lastFlag;

  const int tid = threadIdx.x;
  const int lane = tid & 63;
  const int wave = tid >> 6;
  const int wr = wave >> 1;  // 64-row band within the 128x128 tile
  const int wc = wave & 1;   // 64-col band
  const int fr = lane & 15;
  const int h = lane >> 4;

  // contiguous chunk [t0, t1) of triangle tiles (8 or 9 per block)
  const int t0 = (int)(((long)blockIdx.x * NBLK) >> 8);
  const int t1 = (int)(((long)(blockIdx.x + 1) * NBLK) >> 8);

  int rem = t0, bi = 0;
  while (rem >= NB - bi) { rem -= NB - bi; ++bi; }
  int bj = bi + rem;

  stage_strip(An + (size_t)bi * 65536, sA, tid);
  stage_strip(An + (size_t)bj * 65536, sB, tid);
  __syncthreads();  // drains vmcnt -> tiles resident

  // per-lane fragment base: one b128 per (rowgrp, p) covers ks=2p, 2p+1
  const int fbase = fr * 64 + ((h ^ (fr >> 2)) & 3) * 16;
  const u8* pa = sA + wr * 32768 + fbase;
  const u8* pb = sB + wc * 32768 + fbase;

  for (int t = t0; t < t1; ++t) {
    fp32x4 acc[4][4] = {};
    // full-K compute: no barriers; 64 ds_read_b128 + 512 MFMA per wave
#pragma unroll
    for (int p = 0; p < 8; ++p) {
      lx2 a[4], b[4];
#pragma unroll
      for (int i = 0; i < 4; ++i) {
        a[i] = *(const lx2*)(pa + i * 8192 + p * 1024);
        b[i] = *(const lx2*)(pb + i * 8192 + p * 1024);
      }
#pragma unroll
      for (int i = 0; i < 4; ++i)
#pragma unroll
        for (int j = 0; j < 4; ++j)
          acc[i][j] = __builtin_amdgcn_mfma_f32_16x16x32_fp8_fp8(
              a[i][0], b[j][0], acc[i][j], 0, 0, 0);
#pragma unroll
      for (int i = 0; i < 4; ++i)
#pragma unroll
        for (int j = 0; j < 4; ++j)
          acc[i][j] = __builtin_amdgcn_mfma_f32_16x16x32_fp8_fp8(
              a[i][1], b[j][1], acc[i][j], 0, 0, 0);
    }
    __syncthreads();  // every wave done reading sA/sB

    // issue next tile's staging NOW; the DMA runs under the epilogue below
    int nbi = bi, nbj = bj + 1;
    if (nbj == NB) { ++nbi; nbj = nbi; }
    if (t + 1 < t1) {
      if (nbi != bi) stage_strip(An + (size_t)nbi * 65536, sA, tid);
      stage_strip(An + (size_t)nbj * 65536, sB, tid);
    }

    // Epilogue (register-only + atomics; safe while DMA overwrites LDS).
    // acc = sim*10*log2e -> e = 2^acc via v_exp_f32, no per-elem multiply.
    // C/D layout: col = lane&15, row = (lane>>4)*4 + reg.
    const bool diag = (bi == bj);
    const int rowBase = bi * TILE;
    const int colBase = bj * TILE;
    const int rq = h * 4;
    float posPart = 0.0f;
    float colAcc[4] = {0.0f, 0.0f, 0.0f, 0.0f};
#pragma unroll
    for (int i = 0; i < 4; ++i) {
      const int rbase = rowBase + wr * 64 + i * 16 + rq;
      float rs[4] = {0.0f, 0.0f, 0.0f, 0.0f};
#pragma unroll
      for (int j = 0; j < 4; ++j) {
        const int colg = colBase + wc * 64 + j * 16 + fr;
        fp32x4 v = acc[i][j];
#pragma unroll
        for (int rg = 0; rg < 4; ++rg) {
          const int rowg = rbase + rg;
          float e = __builtin_amdgcn_exp2f(v[rg]);
          if (diag && rowg == colg) e = 0.0f;  // exclude exact diagonal
          rs[rg] += e;
          colAcc[j] += e;
          // positives (upper copy): recover sim*10 = acc*ln2; doubled later
          if (colg == rowg + BS) posPart += v[rg] * LN2;
        }
      }
#pragma unroll
      for (int rg = 0; rg < 4; ++rg) {
        float s = rs[rg];
        s += __shfl_xor(s, 1);
        s += __shfl_xor(s, 2);
        s += __shfl_xor(s, 4);
        s += __shfl_xor(s, 8);
        if (fr == 0) atomicAdd(&den[rbase + rg], s);
      }
    }
    if (!diag) {
#pragma unroll
      for (int j = 0; j < 4; ++j) {
        float c = colAcc[j];
        c += __shfl_xor(c, 16);
        c += __shfl_xor(c, 32);
        if (h == 0) atomicAdd(&den[colBase + wc * 64 + j * 16 + fr], c);
      }
    }
    posPart += __shfl_xor(posPart, 1);
    posPart += __shfl_xor(posPart, 2);
    posPart += __shfl_xor(posPart, 4);
    posPart += __shfl_xor(posPart, 8);
    posPart += __shfl_xor(posPart, 16);
    posPart += __shfl_xor(posPart, 32);
    if (lane == 0 && posPart != 0.0f) atomicAdd(posAcc, posPart);

    __syncthreads();  // drains vmcnt -> next tile staged; LDS reuse safe
    bi = nbi;
    bj = nbj;
  }

  // ---- fused finalize: last block to finish computes the loss ----
  __threadfence();  // device-scope: den/posAcc atomics visible
  if (tid == 0) lastFlag = (atomicAdd(done, 1) == NPBLK - 1);
  __syncthreads();
  if (lastFlag) {
    float s = 0.0f;
    for (int i = tid; i < NROW; i += NTHR)
      s += logf(__hip_atomic_load(&den[i], __ATOMIC_RELAXED,
                                  __HIP_MEMORY_SCOPE_AGENT));
#pragma unroll
    for (int off = 1; off < 64; off <<= 1) s += __shfl_xor(s, off);
    if (lane == 0) redbuf[wave] = s;
    __syncthreads();
    if (tid == 0) {
      float tot = redbuf[0] + redbuf[1] + redbuf[2] + redbuf[3];
      const float pos = __hip_atomic_load(posAcc, __ATOMIC_RELAXED,
                                          __HIP_MEMORY_SCOPE_AGENT);
      // each unordered positive pair was counted once -> double it
      out[0] = (tot - 2.0f * pos) * (1.0f / (float)NROW);
    }
  }
}

extern "C" void kernel_launch(void* const* d_in, const int* in_sizes, int n_in,
                              void* d_out, int out_size, void* d_ws, size_t ws_size,
                              hipStream_t stream) {
  const float* zi = (const float*)d_in[0];
  const float* zj = (const float*)d_in[1];
  float* out = (float*)d_out;

  u8* An = (u8*)d_ws;                                      // 4 MB packed fp8
  float* den = (float*)((char*)d_ws + (size_t)NROW * D);   // 8192 fp32
  float* posAcc = den + NROW;                              // 1 fp32
  int* done = (int*)(posAcc + 1);                          // 1 int

  normalize_k<<<NROW / 4, 256, 0, stream>>>(zi, zj, An, den, posAcc, done);
  gemm_expsum<<<NPBLK, NTHR, 0, stream>>>(An, den, posAcc, done, out);
}

// Round 9
// 137.785 us; speedup vs baseline: 1.5322x; 1.0836x over previous
//
#include <hip/hip_runtime.h>

typedef unsigned char u8;
typedef float fp32x4 __attribute__((ext_vector_type(4)));
typedef long lx2 __attribute__((ext_vector_type(2)));

#define BS 4096
#define NROW 8192
#define D 512
#define TILE 128
#define NB (NROW / TILE)          // 64 block-rows/cols
#define NBLK (NB * (NB + 1) / 2)  // 2080 upper-triangle tiles
#define NPBLK 256                 // persistent workgroups (1 per CU)
#define NTHR 256                  // 4 waves
// An = z_hat * sqrt(10*log2(e))  ->  acc = sim*10*log2(e)  ->
// exp(sim*10) = v_exp_f32(acc) directly (v_exp_f32 computes 2^x).
#define SCALE 3.79828286f
#define LN2 0.69314718f

// Packed An layout (verified R2: bank conflicts 1.28e7 -> 2.1e6).
// 8-byte chunk L = k>>3 of row r:
//   off(r, L) = (r>>4)*8192 + (L>>3)*1024 + (r&15)*64
//             + (((L&3) ^ ((r&15)>>2)) << 4) + (((L>>2)&1) << 3)
// Consumer lane (fr=l&15, h=l>>4): one ds_read_b128 per (rowgrp, p) covering
// ks=2p,2p+1 at rowgrp*8192 + p*1024 + fr*64 + ((h^(fr>>2))&3)*16 ->
// bank-bijective per 16-lane quarter (2 words/bank = structural floor).

__device__ __forceinline__ void g2l16(const void* g, void* l) {
  __builtin_amdgcn_global_load_lds(
      (const __attribute__((address_space(1))) unsigned int*)g,
      (__attribute__((address_space(3))) unsigned int*)l, 16, 0, 0);
}

// stage one 128-row strip (64 KB contiguous) into LDS; 16 g2l16 per thread
__device__ __forceinline__ void stage_strip(const u8* __restrict__ g,
                                            u8* __restrict__ l, int tid) {
#pragma unroll
  for (int it = 0; it < 16; ++it)
    g2l16(g + it * 4096 + tid * 16, l + it * 4096 + tid * 16);
}

// Wave-per-row normalize -> fp8 e4m3 (scaled), packed+swizzled layout.
// Also zeroes den/posAcc/done (ws is re-poisoned before every launch).
__global__ __launch_bounds__(256) void normalize_k(
    const float* __restrict__ zi, const float* __restrict__ zj,
    u8* __restrict__ An, float* __restrict__ den, float* __restrict__ posAcc,
    int* __restrict__ done) {
  const int lane = threadIdx.x & 63;
  const int wave = threadIdx.x >> 6;
  const int r = blockIdx.x * 4 + wave;
  const float* src = (r < BS) ? (zi + (size_t)r * D) : (zj + (size_t)(r - BS) * D);
  const float4 v0 = ((const float4*)src)[lane * 2];
  const float4 v1 = ((const float4*)src)[lane * 2 + 1];
  float ss = v0.x * v0.x + v0.y * v0.y + v0.z * v0.z + v0.w * v0.w +
             v1.x * v1.x + v1.y * v1.y + v1.z * v1.z + v1.w * v1.w;
#pragma unroll
  for (int off = 1; off < 64; off <<= 1) ss += __shfl_xor(ss, off);
  const float inv = SCALE / fmaxf(sqrtf(ss), 1e-8f);
  int lo = __builtin_amdgcn_cvt_pk_fp8_f32(v0.x * inv, v0.y * inv, 0, false);
  lo = __builtin_amdgcn_cvt_pk_fp8_f32(v0.z * inv, v0.w * inv, lo, true);
  int hi = __builtin_amdgcn_cvt_pk_fp8_f32(v1.x * inv, v1.y * inv, 0, false);
  hi = __builtin_amdgcn_cvt_pk_fp8_f32(v1.z * inv, v1.w * inv, hi, true);
  // lane holds chunk L = lane (k = 8*lane .. +8)
  const int r16 = r & 15;
  const int off = ((r >> 4) << 13) + ((lane >> 3) << 10) + (r16 << 6) +
                  ((((lane & 3) ^ (r16 >> 2)) & 3) << 4) + (((lane >> 2) & 1) << 3);
  *(int2*)(An + off) = make_int2(lo, hi);
  if (lane == 0) den[r] = 0.0f;
  if (r == 0 && lane == 0) { posAcc[0] = 0.0f; *done = 0; }
}

// Persistent full-K triangle GEMM (R2 structure, best measured: 69.4us).
// Each block owns ~8 contiguous triangle tiles; LDS holds full-K A and B
// strips -> zero barriers in the K loop. Per tile: compute -> barrier ->
// issue next-tile DMA -> epilogue (overlaps DMA) -> barrier.
// Last block to finish computes the loss. NO __threadfence in the tail:
// its buffer_wbl2/buffer_inv (L2 writeback-invalidate) measured +15-19us
// across R3/R4/R6/R8 vs the fence-free R0/R2. Cross-block data flows only
// through device-scope atomics (LLC-homed); s_waitcnt vmcnt(0) suffices.
__global__ __launch_bounds__(NTHR) void gemm_expsum(
    const u8* __restrict__ An, float* __restrict__ den,
    float* __restrict__ posAcc, int* __restrict__ done,
    float* __restrict__ out) {
  __shared__ __align__(16) u8 sA[TILE * D];  // 64 KB
  __shared__ __align__(16) u8 sB[TILE * D];  // 64 KB
  __shared__ float redbuf[4];
  __shared__ int lastFlag;

  const int tid = threadIdx.x;
  const int lane = tid & 63;
  const int wave = tid >> 6;
  const int wr = wave >> 1;  // 64-row band within the 128x128 tile
  const int wc = wave & 1;   // 64-col band
  const int fr = lane & 15;
  const int h = lane >> 4;

  // contiguous chunk [t0, t1) of triangle tiles (8 or 9 per block)
  const int t0 = (int)(((long)blockIdx.x * NBLK) >> 8);
  const int t1 = (int)(((long)(blockIdx.x + 1) * NBLK) >> 8);

  int rem = t0, bi = 0;
  while (rem >= NB - bi) { rem -= NB - bi; ++bi; }
  int bj = bi + rem;

  stage_strip(An + (size_t)bi * 65536, sA, tid);
  stage_strip(An + (size_t)bj * 65536, sB, tid);
  __syncthreads();  // drains vmcnt -> tiles resident

  // per-lane fragment base: one b128 per (rowgrp, p) covers ks=2p, 2p+1
  const int fbase = fr * 64 + ((h ^ (fr >> 2)) & 3) * 16;
  const u8* pa = sA + wr * 32768 + fbase;
  const u8* pb = sB + wc * 32768 + fbase;

  for (int t = t0; t < t1; ++t) {
    fp32x4 acc[4][4] = {};
    // full-K compute: no barriers; 64 ds_read_b128 + 512 MFMA per wave
#pragma unroll
    for (int p = 0; p < 8; ++p) {
      lx2 a[4], b[4];
#pragma unroll
      for (int i = 0; i < 4; ++i) {
        a[i] = *(const lx2*)(pa + i * 8192 + p * 1024);
        b[i] = *(const lx2*)(pb + i * 8192 + p * 1024);
      }
#pragma unroll
      for (int i = 0; i < 4; ++i)
#pragma unroll
        for (int j = 0; j < 4; ++j)
          acc[i][j] = __builtin_amdgcn_mfma_f32_16x16x32_fp8_fp8(
              a[i][0], b[j][0], acc[i][j], 0, 0, 0);
#pragma unroll
      for (int i = 0; i < 4; ++i)
#pragma unroll
        for (int j = 0; j < 4; ++j)
          acc[i][j] = __builtin_amdgcn_mfma_f32_16x16x32_fp8_fp8(
              a[i][1], b[j][1], acc[i][j], 0, 0, 0);
    }
    __syncthreads();  // every wave done reading sA/sB

    // issue next tile's staging NOW; the DMA runs under the epilogue below
    int nbi = bi, nbj = bj + 1;
    if (nbj == NB) { ++nbi; nbj = nbi; }
    if (t + 1 < t1) {
      if (nbi != bi) stage_strip(An + (size_t)nbi * 65536, sA, tid);
      stage_strip(An + (size_t)nbj * 65536, sB, tid);
    }

    // Epilogue (register-only + atomics; safe while DMA overwrites LDS).
    // acc = sim*10*log2e -> e = 2^acc via v_exp_f32, no per-elem multiply.
    // C/D layout: col = lane&15, row = (lane>>4)*4 + reg.
    const bool diag = (bi == bj);
    const int rowBase = bi * TILE;
    const int colBase = bj * TILE;
    const int rq = h * 4;
    float posPart = 0.0f;
    float colAcc[4] = {0.0f, 0.0f, 0.0f, 0.0f};
#pragma unroll
    for (int i = 0; i < 4; ++i) {
      const int rbase = rowBase + wr * 64 + i * 16 + rq;
      float rs[4] = {0.0f, 0.0f, 0.0f, 0.0f};
#pragma unroll
      for (int j = 0; j < 4; ++j) {
        const int colg = colBase + wc * 64 + j * 16 + fr;
        fp32x4 v = acc[i][j];
#pragma unroll
        for (int rg = 0; rg < 4; ++rg) {
          const int rowg = rbase + rg;
          float e = __builtin_amdgcn_exp2f(v[rg]);
          if (diag && rowg == colg) e = 0.0f;  // exclude exact diagonal
          rs[rg] += e;
          colAcc[j] += e;
          // positives (upper copy): recover sim*10 = acc*ln2; doubled later
          if (colg == rowg + BS) posPart += v[rg] * LN2;
        }
      }
#pragma unroll
      for (int rg = 0; rg < 4; ++rg) {
        float s = rs[rg];
        s += __shfl_xor(s, 1);
        s += __shfl_xor(s, 2);
        s += __shfl_xor(s, 4);
        s += __shfl_xor(s, 8);
        if (fr == 0) atomicAdd(&den[rbase + rg], s);
      }
    }
    if (!diag) {
#pragma unroll
      for (int j = 0; j < 4; ++j) {
        float c = colAcc[j];
        c += __shfl_xor(c, 16);
        c += __shfl_xor(c, 32);
        if (h == 0) atomicAdd(&den[colBase + wc * 64 + j * 16 + fr], c);
      }
    }
    posPart += __shfl_xor(posPart, 1);
    posPart += __shfl_xor(posPart, 2);
    posPart += __shfl_xor(posPart, 4);
    posPart += __shfl_xor(posPart, 8);
    posPart += __shfl_xor(posPart, 16);
    posPart += __shfl_xor(posPart, 32);
    if (lane == 0 && posPart != 0.0f) atomicAdd(posAcc, posPart);

    __syncthreads();  // drains vmcnt -> next tile staged; LDS reuse safe
    bi = nbi;
    bj = nbj;
  }

  // ---- fused finalize (fence-free): last block computes the loss ----
  // Our den/posAcc atomics are device-scope (LLC-homed). Wait for OUR
  // outstanding memory ops to complete, then publish via relaxed RMW.
  // No buffer_wbl2 / buffer_inv (that was the +19us of __threadfence).
  asm volatile("s_waitcnt vmcnt(0)" ::: "memory");
  if (tid == 0)
    lastFlag = (__hip_atomic_fetch_add(done, 1, __ATOMIC_RELAXED,
                                       __HIP_MEMORY_SCOPE_AGENT) == NPBLK - 1);
  __syncthreads();
  if (lastFlag) {
    float s = 0.0f;
    for (int i = tid; i < NROW; i += NTHR)
      s += logf(__hip_atomic_load(&den[i], __ATOMIC_RELAXED,
                                  __HIP_MEMORY_SCOPE_AGENT));
#pragma unroll
    for (int off = 1; off < 64; off <<= 1) s += __shfl_xor(s, off);
    if (lane == 0) redbuf[wave] = s;
    __syncthreads();
    if (tid == 0) {
      float tot = redbuf[0] + redbuf[1] + redbuf[2] + redbuf[3];
      const float pos = __hip_atomic_load(posAcc, __ATOMIC_RELAXED,
                                          __HIP_MEMORY_SCOPE_AGENT);
      // each unordered positive pair was counted once -> double it
      out[0] = (tot - 2.0f * pos) * (1.0f / (float)NROW);
    }
  }
}

extern "C" void kernel_launch(void* const* d_in, const int* in_sizes, int n_in,
                              void* d_out, int out_size, void* d_ws, size_t ws_size,
                              hipStream_t stream) {
  const float* zi = (const float*)d_in[0];
  const float* zj = (const float*)d_in[1];
  float* out = (float*)d_out;

  u8* An = (u8*)d_ws;                                      // 4 MB packed fp8
  float* den = (float*)((char*)d_ws + (size_t)NROW * D);   // 8192 fp32
  float* posAcc = den + NROW;                              // 1 fp32
  int* done = (int*)(posAcc + 1);                          // 1 int

  normalize_k<<<NROW / 4, 256, 0, stream>>>(zi, zj, An, den, posAcc, done);
  gemm_expsum<<<NPBLK, NTHR, 0, stream>>>(An, den, posAcc, done, out);
}

// Round 10
// 129.848 us; speedup vs baseline: 1.6259x; 1.0611x over previous
//
#include <hip/hip_runtime.h>

typedef unsigned char u8;
typedef float fp32x4 __attribute__((ext_vector_type(4)));
typedef long lx2 __attribute__((ext_vector_type(2)));

#define BS 4096
#define NROW 8192
#define D 512
#define TILE 128
#define NB (NROW / TILE)          // 64 block-rows/cols
#define NBLK (NB * (NB + 1) / 2)  // 2080 upper-triangle tiles
#define NPBLK 256                 // persistent workgroups (1 per CU)
#define NTHR 256                  // 4 waves
// An = z_hat * sqrt(10*log2(e))  ->  acc = sim*10*log2(e)  ->
// exp(sim*10) = v_exp_f32(acc) directly (v_exp_f32 computes 2^x).
#define SCALE 3.79828286f
#define LN2 0.69314718f

// Packed An layout (verified R2: bank conflicts 1.28e7 -> 2.1e6).
// 8-byte chunk L = k>>3 of row r:
//   off(r, L) = (r>>4)*8192 + (L>>3)*1024 + (r&15)*64
//             + (((L&3) ^ ((r&15)>>2)) << 4) + (((L>>2)&1) << 3)
// Consumer lane (fr=l&15, h=l>>4): one ds_read_b128 per (rowgrp, p) covering
// ks=2p,2p+1 at rowgrp*8192 + p*1024 + fr*64 + ((h^(fr>>2))&3)*16 ->
// bank-bijective per 16-lane quarter (2 words/bank = structural floor).

__device__ __forceinline__ void g2l16(const void* g, void* l) {
  __builtin_amdgcn_global_load_lds(
      (const __attribute__((address_space(1))) unsigned int*)g,
      (__attribute__((address_space(3))) unsigned int*)l, 16, 0, 0);
}

// stage one 128-row strip (64 KB contiguous) into LDS; 16 g2l16 per thread
__device__ __forceinline__ void stage_strip(const u8* __restrict__ g,
                                            u8* __restrict__ l, int tid) {
#pragma unroll
  for (int it = 0; it < 16; ++it)
    g2l16(g + it * 4096 + tid * 16, l + it * 4096 + tid * 16);
}

// Wave-per-row normalize -> fp8 e4m3 (scaled), packed+swizzled layout.
// Also zeroes den/posAcc/done (ws is re-poisoned before every launch).
__global__ __launch_bounds__(256) void normalize_k(
    const float* __restrict__ zi, const float* __restrict__ zj,
    u8* __restrict__ An, float* __restrict__ den, float* __restrict__ posAcc,
    int* __restrict__ done) {
  const int lane = threadIdx.x & 63;
  const int wave = threadIdx.x >> 6;
  const int r = blockIdx.x * 4 + wave;
  const float* src = (r < BS) ? (zi + (size_t)r * D) : (zj + (size_t)(r - BS) * D);
  const float4 v0 = ((const float4*)src)[lane * 2];
  const float4 v1 = ((const float4*)src)[lane * 2 + 1];
  float ss = v0.x * v0.x + v0.y * v0.y + v0.z * v0.z + v0.w * v0.w +
             v1.x * v1.x + v1.y * v1.y + v1.z * v1.z + v1.w * v1.w;
#pragma unroll
  for (int off = 1; off < 64; off <<= 1) ss += __shfl_xor(ss, off);
  const float inv = SCALE / fmaxf(sqrtf(ss), 1e-8f);
  int lo = __builtin_amdgcn_cvt_pk_fp8_f32(v0.x * inv, v0.y * inv, 0, false);
  lo = __builtin_amdgcn_cvt_pk_fp8_f32(v0.z * inv, v0.w * inv, lo, true);
  int hi = __builtin_amdgcn_cvt_pk_fp8_f32(v1.x * inv, v1.y * inv, 0, false);
  hi = __builtin_amdgcn_cvt_pk_fp8_f32(v1.z * inv, v1.w * inv, hi, true);
  // lane holds chunk L = lane (k = 8*lane .. +8)
  const int r16 = r & 15;
  const int off = ((r >> 4) << 13) + ((lane >> 3) << 10) + (r16 << 6) +
                  ((((lane & 3) ^ (r16 >> 2)) & 3) << 4) + (((lane >> 2) & 1) << 3);
  *(int2*)(An + off) = make_int2(lo, hi);
  if (lane == 0) den[r] = 0.0f;
  if (r == 0 && lane == 0) { posAcc[0] = 0.0f; *done = 0; }
}

// Persistent full-K triangle GEMM (R2 structure, best measured core).
// Each block owns ~8 contiguous triangle tiles; LDS holds full-K A and B
// strips -> zero barriers in the K loop. Per tile: compute -> barrier ->
// issue next-tile DMA -> epilogue (overlaps DMA) -> barrier.
// Tail: NO __threadfence (its buffer_wbl2/buffer_inv cost +15-19us,
// R3/R4/R6/R8 vs R0/R2; removal verified R9 -11us). Finalize loads are
// BATCHED (32 independent agent-scope loads in flight, then math) -- the
// serial load->logf loop cost ~10us on the critical path in R9.
__global__ __launch_bounds__(NTHR) void gemm_expsum(
    const u8* __restrict__ An, float* __restrict__ den,
    float* __restrict__ posAcc, int* __restrict__ done,
    float* __restrict__ out) {
  __shared__ __align__(16) u8 sA[TILE * D];  // 64 KB
  __shared__ __align__(16) u8 sB[TILE * D];  // 64 KB
  __shared__ float redbuf[4];
  __shared__ int lastFlag;

  const int tid = threadIdx.x;
  const int lane = tid & 63;
  const int wave = tid >> 6;
  const int wr = wave >> 1;  // 64-row band within the 128x128 tile
  const int wc = wave & 1;   // 64-col band
  const int fr = lane & 15;
  const int h = lane >> 4;

  // contiguous chunk [t0, t1) of triangle tiles (8 or 9 per block)
  const int t0 = (int)(((long)blockIdx.x * NBLK) >> 8);
  const int t1 = (int)(((long)(blockIdx.x + 1) * NBLK) >> 8);

  int rem = t0, bi = 0;
  while (rem >= NB - bi) { rem -= NB - bi; ++bi; }
  int bj = bi + rem;

  stage_strip(An + (size_t)bi * 65536, sA, tid);
  stage_strip(An + (size_t)bj * 65536, sB, tid);
  __syncthreads();  // drains vmcnt -> tiles resident

  // per-lane fragment base: one b128 per (rowgrp, p) covers ks=2p, 2p+1
  const int fbase = fr * 64 + ((h ^ (fr >> 2)) & 3) * 16;
  const u8* pa = sA + wr * 32768 + fbase;
  const u8* pb = sB + wc * 32768 + fbase;

  for (int t = t0; t < t1; ++t) {
    fp32x4 acc[4][4] = {};
    // full-K compute: no barriers; 64 ds_read_b128 + 512 MFMA per wave
#pragma unroll
    for (int p = 0; p < 8; ++p) {
      lx2 a[4], b[4];
#pragma unroll
      for (int i = 0; i < 4; ++i) {
        a[i] = *(const lx2*)(pa + i * 8192 + p * 1024);
        b[i] = *(const lx2*)(pb + i * 8192 + p * 1024);
      }
#pragma unroll
      for (int i = 0; i < 4; ++i)
#pragma unroll
        for (int j = 0; j < 4; ++j)
          acc[i][j] = __builtin_amdgcn_mfma_f32_16x16x32_fp8_fp8(
              a[i][0], b[j][0], acc[i][j], 0, 0, 0);
#pragma unroll
      for (int i = 0; i < 4; ++i)
#pragma unroll
        for (int j = 0; j < 4; ++j)
          acc[i][j] = __builtin_amdgcn_mfma_f32_16x16x32_fp8_fp8(
              a[i][1], b[j][1], acc[i][j], 0, 0, 0);
    }
    __syncthreads();  // every wave done reading sA/sB

    // issue next tile's staging NOW; the DMA runs under the epilogue below
    int nbi = bi, nbj = bj + 1;
    if (nbj == NB) { ++nbi; nbj = nbi; }
    if (t + 1 < t1) {
      if (nbi != bi) stage_strip(An + (size_t)nbi * 65536, sA, tid);
      stage_strip(An + (size_t)nbj * 65536, sB, tid);
    }

    // Epilogue (register-only + atomics; safe while DMA overwrites LDS).
    // acc = sim*10*log2e -> e = 2^acc via v_exp_f32, no per-elem multiply.
    // C/D layout: col = lane&15, row = (lane>>4)*4 + reg.
    const bool diag = (bi == bj);
    const int rowBase = bi * TILE;
    const int colBase = bj * TILE;
    const int rq = h * 4;
    float posPart = 0.0f;
    float colAcc[4] = {0.0f, 0.0f, 0.0f, 0.0f};
#pragma unroll
    for (int i = 0; i < 4; ++i) {
      const int rbase = rowBase + wr * 64 + i * 16 + rq;
      float rs[4] = {0.0f, 0.0f, 0.0f, 0.0f};
#pragma unroll
      for (int j = 0; j < 4; ++j) {
        const int colg = colBase + wc * 64 + j * 16 + fr;
        fp32x4 v = acc[i][j];
#pragma unroll
        for (int rg = 0; rg < 4; ++rg) {
          const int rowg = rbase + rg;
          float e = __builtin_amdgcn_exp2f(v[rg]);
          if (diag && rowg == colg) e = 0.0f;  // exclude exact diagonal
          rs[rg] += e;
          colAcc[j] += e;
          // positives (upper copy): recover sim*10 = acc*ln2; doubled later
          if (colg == rowg + BS) posPart += v[rg] * LN2;
        }
      }
#pragma unroll
      for (int rg = 0; rg < 4; ++rg) {
        float s = rs[rg];
        s += __shfl_xor(s, 1);
        s += __shfl_xor(s, 2);
        s += __shfl_xor(s, 4);
        s += __shfl_xor(s, 8);
        if (fr == 0) atomicAdd(&den[rbase + rg], s);
      }
    }
    if (!diag) {
#pragma unroll
      for (int j = 0; j < 4; ++j) {
        float c = colAcc[j];
        c += __shfl_xor(c, 16);
        c += __shfl_xor(c, 32);
        if (h == 0) atomicAdd(&den[colBase + wc * 64 + j * 16 + fr], c);
      }
    }
    posPart += __shfl_xor(posPart, 1);
    posPart += __shfl_xor(posPart, 2);
    posPart += __shfl_xor(posPart, 4);
    posPart += __shfl_xor(posPart, 8);
    posPart += __shfl_xor(posPart, 16);
    posPart += __shfl_xor(posPart, 32);
    if (lane == 0 && posPart != 0.0f) atomicAdd(posAcc, posPart);

    __syncthreads();  // drains vmcnt -> next tile staged; LDS reuse safe
    bi = nbi;
    bj = nbj;
  }

  // ---- fused finalize (fence-free): last block computes the loss ----
  // den/posAcc flow only through device-scope atomics (LLC-homed); our
  // outstanding ops drain with vmcnt(0), then publish via relaxed RMW.
  asm volatile("s_waitcnt vmcnt(0)" ::: "memory");
  if (tid == 0)
    lastFlag = (__hip_atomic_fetch_add(done, 1, __ATOMIC_RELAXED,
                                       __HIP_MEMORY_SCOPE_AGENT) == NPBLK - 1);
  __syncthreads();
  if (lastFlag) {
    // batched loads: all 32 per-thread agent-scope loads issued before use
    // (fully unrolled, compile-time indices -> registers, rule #20)
    float v[32];
#pragma unroll
    for (int io = 0; io < 32; ++io)
      v[io] = __hip_atomic_load(&den[tid + io * NTHR], __ATOMIC_RELAXED,
                                __HIP_MEMORY_SCOPE_AGENT);
    float s = 0.0f;
#pragma unroll
    for (int io = 0; io < 32; ++io)
      s += __builtin_amdgcn_logf(v[io]);  // log2; *ln2 once at the end
#pragma unroll
    for (int off = 1; off < 64; off <<= 1) s += __shfl_xor(s, off);
    if (lane == 0) redbuf[wave] = s;
    __syncthreads();
    if (tid == 0) {
      const float tot =
          (redbuf[0] + redbuf[1] + redbuf[2] + redbuf[3]) * LN2;  // -> ln
      const float pos = __hip_atomic_load(posAcc, __ATOMIC_RELAXED,
                                          __HIP_MEMORY_SCOPE_AGENT);
      // each unordered positive pair was counted once -> double it
      out[0] = (tot - 2.0f * pos) * (1.0f / (float)NROW);
    }
  }
}

extern "C" void kernel_launch(void* const* d_in, const int* in_sizes, int n_in,
                              void* d_out, int out_size, void* d_ws, size_t ws_size,
                              hipStream_t stream) {
  const float* zi = (const float*)d_in[0];
  const float* zj = (const float*)d_in[1];
  float* out = (float*)d_out;

  u8* An = (u8*)d_ws;                                      // 4 MB packed fp8
  float* den = (float*)((char*)d_ws + (size_t)NROW * D);   // 8192 fp32
  float* posAcc = den + NROW;                              // 1 fp32
  int* done = (int*)(posAcc + 1);                          // 1 int

  normalize_k<<<NROW / 4, 256, 0, stream>>>(zi, zj, An, den, posAcc, done);
  gemm_expsum<<<NPBLK, NTHR, 0, stream>>>(An, den, posAcc, done, out);
}

// Round 11
// 112.956 us; speedup vs baseline: 1.8690x; 1.1495x over previous
//
#include <hip/hip_runtime.h>

typedef unsigned char u8;
typedef float fp32x4 __attribute__((ext_vector_type(4)));
typedef long lx2 __attribute__((ext_vector_type(2)));

#define BS 4096
#define NROW 8192
#define D 512
#define NB64 128                    // 64-row bands
#define NT64 (NB64 * (NB64 + 1) / 2)  // 8256 upper-triangle 64x64 wave-tiles
#define NPBLK 512                   // 2 blocks/CU, 4 waves each -> 2048 waves
#define NTHR 256
// An = z_hat * sqrt(10*log2(e)) -> acc = sim*10*log2e -> exp(sim*10)=2^acc.
#define SCALE 3.79828286f
#define LN2 0.69314718f

// Packed An layout (verified R2/R4: conflict-free LDS reads AND perfectly
// coalesced 1KB-contiguous global reads per (rowgroup, p) per wave).
// 8-byte chunk L = k>>3 of row r:
//   off(r, L) = (r>>4)*8192 + (L>>3)*1024 + (r&15)*64
//             + (((L&3) ^ ((r&15)>>2)) << 4) + (((L>>2)&1) << 3)
// Fragment for lane (fr=l&15, h=l>>4), rowgroup g, k-pair p is the 16 B at
//   g*8192 + p*1024 + fr*64 + ((h^(fr>>2))&3)*16   (one lx2 = ks 2p, 2p+1)

// Wave-per-row normalize -> fp8 e4m3 (scaled), packed layout.
// Also zeroes den + counters (ws is re-poisoned before every launch).
__global__ __launch_bounds__(256) void normalize_k(
    const float* __restrict__ zi, const float* __restrict__ zj,
    u8* __restrict__ An, float* __restrict__ den, float* __restrict__ posAcc,
    int* __restrict__ ctrs) {
  const int lane = threadIdx.x & 63;
  const int wave = threadIdx.x >> 6;
  const int r = blockIdx.x * 4 + wave;
  const float* src = (r < BS) ? (zi + (size_t)r * D) : (zj + (size_t)(r - BS) * D);
  const float4 v0 = ((const float4*)src)[lane * 2];
  const float4 v1 = ((const float4*)src)[lane * 2 + 1];
  float ss = v0.x * v0.x + v0.y * v0.y + v0.z * v0.z + v0.w * v0.w +
             v1.x * v1.x + v1.y * v1.y + v1.z * v1.z + v1.w * v1.w;
#pragma unroll
  for (int off = 1; off < 64; off <<= 1) ss += __shfl_xor(ss, off);
  const float inv = SCALE / fmaxf(sqrtf(ss), 1e-8f);
  int lo = __builtin_amdgcn_cvt_pk_fp8_f32(v0.x * inv, v0.y * inv, 0, false);
  lo = __builtin_amdgcn_cvt_pk_fp8_f32(v0.z * inv, v0.w * inv, lo, true);
  int hi = __builtin_amdgcn_cvt_pk_fp8_f32(v1.x * inv, v1.y * inv, 0, false);
  hi = __builtin_amdgcn_cvt_pk_fp8_f32(v1.z * inv, v1.w * inv, hi, true);
  // lane holds chunk L = lane (k = 8*lane .. +8)
  const int r16 = r & 15;
  const int off = ((r >> 4) << 13) + ((lane >> 3) << 10) + (r16 << 6) +
                  ((((lane & 3) ^ (r16 >> 2)) & 3) << 4) + (((lane >> 2) & 1) << 3);
  *(int2*)(An + off) = make_int2(lo, hi);
  if (lane == 0) den[r] = 0.0f;
  if (blockIdx.x == 0) {
    if (threadIdx.x == 0) posAcc[0] = 0.0f;
    for (int z = threadIdx.x; z < 288; z += 256) ctrs[z] = 0;
  }
}

// Wave-owned 64x64 triangle tiles: ZERO LDS, ZERO barriers in the hot loop.
// A band (64 rows x full K) lives in VGPRs (aF[4][8] lx2 = 128 VGPR,
// static indices); B streamed from L2 (coalesced, 1-p-step prefetch).
// Diag tiles use aF for both operands (no B reads). 8 waves/CU cross-hide
// epilogue VALU and B latency. Tail: per-wave vmcnt drain -> block barrier
// -> hierarchical publish (8x64 RMW, padded lines) -> last block finalizes.
__global__ __launch_bounds__(NTHR, 2) void gemm_expsum(
    const u8* __restrict__ An, float* __restrict__ den,
    float* __restrict__ posAcc, int* __restrict__ ctrs,
    float* __restrict__ out) {
  __shared__ float redbuf[4];
  __shared__ int lastFlag;

  const int tid = threadIdx.x;
  const int lane = tid & 63;
  const int wave = tid >> 6;
  const int fr = lane & 15;
  const int h = lane >> 4;
  const int fbase = fr * 64 + ((h ^ (fr >> 2)) & 3) * 16;
  const u8* gaBase = An + fbase;

  // XCD-contiguous chunking: blocks on one XCD cover a contiguous tile range
  const int bid = (int)((blockIdx.x & 7) * (NPBLK / 8) + (blockIdx.x >> 3));
  const int wid = bid * 4 + wave;
  const int t0 = (int)(((long)wid * NT64) >> 11);
  const int t1 = (int)(((long)(wid + 1) * NT64) >> 11);

  int rem = t0, bi = 0;
  while (rem >= NB64 - bi) { rem -= NB64 - bi; ++bi; }
  int bj = bi + rem;

  lx2 aF[4][8];
  auto loadA = [&](int band) {
#pragma unroll
    for (int i = 0; i < 4; ++i) {
      const u8* ga = gaBase + (size_t)(band * 4 + i) * 8192;
#pragma unroll
      for (int p = 0; p < 8; ++p) aF[i][p] = *(const lx2*)(ga + p * 1024);
    }
  };
  loadA(bi);

  for (int t = t0; t < t1; ++t) {
    const bool diag = (bi == bj);
    fp32x4 acc[4][4] = {};

    if (diag) {
      // B == A: pure-register K loop
#pragma unroll
      for (int p = 0; p < 8; ++p) {
#pragma unroll
        for (int i = 0; i < 4; ++i)
#pragma unroll
          for (int j = 0; j < 4; ++j)
            acc[i][j] = __builtin_amdgcn_mfma_f32_16x16x32_fp8_fp8(
                aF[i][p][0], aF[j][p][0], acc[i][j], 0, 0, 0);
#pragma unroll
        for (int i = 0; i < 4; ++i)
#pragma unroll
          for (int j = 0; j < 4; ++j)
            acc[i][j] = __builtin_amdgcn_mfma_f32_16x16x32_fp8_fp8(
                aF[i][p][1], aF[j][p][1], acc[i][j], 0, 0, 0);
      }
    } else {
      const u8* gb = gaBase + (size_t)bj * 4 * 8192;
      lx2 bb[2][4];
#pragma unroll
      for (int j = 0; j < 4; ++j) bb[0][j] = *(const lx2*)(gb + j * 8192);
#pragma unroll
      for (int p = 0; p < 8; ++p) {
        if (p < 7) {
#pragma unroll
          for (int j = 0; j < 4; ++j)
            bb[(p + 1) & 1][j] = *(const lx2*)(gb + j * 8192 + (p + 1) * 1024);
        }
#pragma unroll
        for (int i = 0; i < 4; ++i)
#pragma unroll
          for (int j = 0; j < 4; ++j)
            acc[i][j] = __builtin_amdgcn_mfma_f32_16x16x32_fp8_fp8(
                aF[i][p][0], bb[p & 1][j][0], acc[i][j], 0, 0, 0);
#pragma unroll
        for (int i = 0; i < 4; ++i)
#pragma unroll
          for (int j = 0; j < 4; ++j)
            acc[i][j] = __builtin_amdgcn_mfma_f32_16x16x32_fp8_fp8(
                aF[i][p][1], bb[p & 1][j][1], acc[i][j], 0, 0, 0);
      }
    }

    // Epilogue. acc = sim*10*log2e -> e = 2^acc. C/D layout:
    // col = lane&15, row = (lane>>4)*4 + reg.
    const int rowBase = bi * 64;
    const int colBase = bj * 64;
    const int rq = h * 4;
    float posPart = 0.0f;
    float colAcc[4] = {0.0f, 0.0f, 0.0f, 0.0f};
#pragma unroll
    for (int i = 0; i < 4; ++i) {
      const int rbase = rowBase + i * 16 + rq;
      float rs[4] = {0.0f, 0.0f, 0.0f, 0.0f};
#pragma unroll
      for (int j = 0; j < 4; ++j) {
        const int colg = colBase + j * 16 + fr;
        fp32x4 v = acc[i][j];
#pragma unroll
        for (int rg = 0; rg < 4; ++rg) {
          const int rowg = rbase + rg;
          float e = __builtin_amdgcn_exp2f(v[rg]);
          if (diag && rowg == colg) e = 0.0f;  // exclude exact diagonal
          rs[rg] += e;
          colAcc[j] += e;
          // positives (upper copy): recover sim*10 = acc*ln2; doubled later
          if (colg == rowg + BS) posPart += v[rg] * LN2;
        }
      }
#pragma unroll
      for (int rg = 0; rg < 4; ++rg) {
        float s = rs[rg];
        s += __shfl_xor(s, 1);
        s += __shfl_xor(s, 2);
        s += __shfl_xor(s, 4);
        s += __shfl_xor(s, 8);
        if (fr == 0) atomicAdd(&den[rbase + rg], s);
      }
    }
    if (!diag) {
#pragma unroll
      for (int j = 0; j < 4; ++j) {
        float c = colAcc[j];
        c += __shfl_xor(c, 16);
        c += __shfl_xor(c, 32);
        if (h == 0) atomicAdd(&den[colBase + j * 16 + fr], c);
      }
    }
    posPart += __shfl_xor(posPart, 1);
    posPart += __shfl_xor(posPart, 2);
    posPart += __shfl_xor(posPart, 4);
    posPart += __shfl_xor(posPart, 8);
    posPart += __shfl_xor(posPart, 16);
    posPart += __shfl_xor(posPart, 32);
    if (lane == 0 && posPart != 0.0f) atomicAdd(posAcc, posPart);

    // advance; reload A band only when the row band changes
    ++bj;
    if (bj == NB64) {
      ++bi;
      bj = bi;
      if (t + 1 < t1) loadA(bi);
    }
  }

  // ---- fence-free tail (no buffer_wbl2/inv: that was +15-19us, R8->R9) --
  // each wave drains its own atomics, THEN the block barrier, THEN publish
  // (fixes R10's latent publish-before-peer-drain window).
  asm volatile("s_waitcnt vmcnt(0)" ::: "memory");
  __syncthreads();
  if (tid == 0) {
    // hierarchical publish: 8 padded group counters then a master counter
    const int g = (int)(blockIdx.x & 7);
    int last = 0;
    if (__hip_atomic_fetch_add(&ctrs[32 + g * 32], 1, __ATOMIC_RELAXED,
                               __HIP_MEMORY_SCOPE_AGENT) == NPBLK / 8 - 1)
      last = (__hip_atomic_fetch_add(&ctrs[0], 1, __ATOMIC_RELAXED,
                                     __HIP_MEMORY_SCOPE_AGENT) == 7);
    lastFlag = last;
  }
  __syncthreads();
  if (lastFlag) {
    // batched: all 32 per-thread agent-scope loads in flight before use
    float v[32];
#pragma unroll
    for (int io = 0; io < 32; ++io)
      v[io] = __hip_atomic_load(&den[tid + io * NTHR], __ATOMIC_RELAXED,
                                __HIP_MEMORY_SCOPE_AGENT);
    float s = 0.0f;
#pragma unroll
    for (int io = 0; io < 32; ++io)
      s += __builtin_amdgcn_logf(v[io]);  // log2; *ln2 once at the end
#pragma unroll
    for (int off = 1; off < 64; off <<= 1) s += __shfl_xor(s, off);
    if (lane == 0) redbuf[wave] = s;
    __syncthreads();
    if (tid == 0) {
      const float tot =
          (redbuf[0] + redbuf[1] + redbuf[2] + redbuf[3]) * LN2;  // -> ln
      const float pos = __hip_atomic_load(posAcc, __ATOMIC_RELAXED,
                                          __HIP_MEMORY_SCOPE_AGENT);
      // each unordered positive pair was counted once -> double it
      out[0] = (tot - 2.0f * pos) * (1.0f / (float)NROW);
    }
  }
}

extern "C" void kernel_launch(void* const* d_in, const int* in_sizes, int n_in,
                              void* d_out, int out_size, void* d_ws, size_t ws_size,
                              hipStream_t stream) {
  const float* zi = (const float*)d_in[0];
  const float* zj = (const float*)d_in[1];
  float* out = (float*)d_out;

  u8* An = (u8*)d_ws;                                      // 4 MB packed fp8
  float* den = (float*)((char*)d_ws + (size_t)NROW * D);   // 8192 fp32
  float* posAcc = den + NROW;                              // 1 fp32
  int* ctrs = (int*)(posAcc + 1);                          // 288 ints (padded)

  normalize_k<<<NROW / 4, 256, 0, stream>>>(zi, zj, An, den, posAcc, ctrs);
  gemm_expsum<<<NPBLK, NTHR, 0, stream>>>(An, den, posAcc, ctrs, out);
}